// Round 6
// baseline (269.880 us; speedup 1.0000x reference)
//
#include <hip/hip_runtime.h>
#include <cstdint>
#include <cstddef>

// x[B=32, T=4096, N=256] fp32 -> z same shape.
// Refractory scan: spike at step t iff x>0 and t >= na; then na = t+6.
// Entry state q==k  <=>  first k steps of chunk blocked (na=k). q in [0,5].
#define BB 32
#define TT 4096
#define NN 256
#define NNV 64        // float4 groups per row
#define CC 32         // chunk length (small -> big grid -> 16 waves/CU)
#define PSUB 4        // chunks per block (one per 64-lane group)
#define PP 128        // chunks per chain (TT/CC)
#define PG 32         // blocks per chain (PP/PSUB)

// ---------------- Kernel A: sign bits + 6-entry exit tables ----------------
__global__ __launch_bounds__(256, 4) void refrac_scan(const float* __restrict__ x,
                                                      uint32_t* __restrict__ tbl,
                                                      uint32_t* __restrict__ bits_g) {
    const int tid = threadIdx.x;
    const int pg = blockIdx.x >> 5;   // chunk-group
    const int b  = blockIdx.x & 31;   // batch
    const int psub = tid >> 6;
    const int n4 = tid & 63;
    const int p = pg * PSUB + psub;   // absolute chunk in [0,128)

    const float4* __restrict__ xv = reinterpret_cast<const float4*>(x)
        + ((size_t)b * TT + (size_t)p * CC) * NNV + n4;

    int na[4][6];
    #pragma unroll
    for (int c = 0; c < 4; ++c)
        #pragma unroll
        for (int e = 0; e < 6; ++e) na[c][e] = e;

    uint32_t cur[4] = {0u, 0u, 0u, 0u};

    #pragma unroll
    for (int jb = 0; jb < CC; jb += 8) {
        float4 buf[8];
        #pragma unroll
        for (int u = 0; u < 8; ++u)
            buf[u] = xv[(size_t)(jb + u) * NNV];
        #pragma unroll
        for (int u = 0; u < 8; ++u) {
            const int j = jb + u;
            const float4 v = buf[u];
            const float fv[4] = {v.x, v.y, v.z, v.w};
            #pragma unroll
            for (int c = 0; c < 4; ++c) {
                const bool pos = fv[c] > 0.0f;
                cur[c] |= pos ? (1u << j) : 0u;
                #pragma unroll
                for (int e = 0; e < 6; ++e)
                    if (pos & (j >= na[c][e])) na[c][e] = j + 6;
            }
        }
    }

    const size_t row = (size_t)b * PP + p;

    uint32_t t4[4];
    #pragma unroll
    for (int c = 0; c < 4; ++c) {
        uint32_t t = 0;
        #pragma unroll
        for (int e = 0; e < 6; ++e) {
            int q = na[c][e] - CC;
            q = q > 0 ? q : 0;                 // exit state in [0,5]
            t |= (uint32_t)q << (4 * e);
        }
        t4[c] = t;
    }
    reinterpret_cast<uint4*>(tbl)[row * NNV + n4] =
        make_uint4(t4[0], t4[1], t4[2], t4[3]);
    reinterpret_cast<uint4*>(bits_g)[row * NNV + n4] =
        make_uint4(cur[0], cur[1], cur[2], cur[3]);
}

// ------- Kernel B: per-chain compose over 128 chunk tables (tiny) -------
__global__ __launch_bounds__(256) void refrac_compose(const uint32_t* __restrict__ tbl,
                                                      uint8_t* __restrict__ entry) {
    const int n = threadIdx.x;
    const int b = blockIdx.x;
    int e = 0;
    for (int pb = 0; pb < PP; pb += 16) {
        uint32_t tv[16];
        #pragma unroll
        for (int i = 0; i < 16; ++i)           // independent, coalesced
            tv[i] = tbl[((size_t)b * PP + pb + i) * NN + n];
        #pragma unroll
        for (int i = 0; i < 16; ++i) {         // dependent nibble lookups
            entry[((size_t)b * PP + pb + i) * NN + n] = (uint8_t)e;
            e = (int)((tv[i] >> (4 * e)) & 0xFu);
        }
    }
}

// ---------------- Kernel C: emit z from bits + entry states ----------------
__global__ __launch_bounds__(256, 4) void refrac_emit(const uint32_t* __restrict__ bits_g,
                                                      const uint8_t* __restrict__ entry,
                                                      float* __restrict__ z) {
    const int tid = threadIdx.x;
    const int pg = blockIdx.x >> 5;
    const int b  = blockIdx.x & 31;
    const int psub = tid >> 6;
    const int n4 = tid & 63;
    const int p = pg * PSUB + psub;

    const size_t row = (size_t)b * PP + p;

    // Entry states of chains 4*n4..4*n4+3 are 4 consecutive bytes -> one u32.
    const uint32_t ew =
        reinterpret_cast<const uint32_t*>(entry)[row * NNV + n4];
    int ea[4];
    #pragma unroll
    for (int c = 0; c < 4; ++c) ea[c] = (int)((ew >> (8 * c)) & 0xFFu);

    const uint4 bv = reinterpret_cast<const uint4*>(bits_g)[row * NNV + n4];
    const uint32_t bw[4] = {bv.x, bv.y, bv.z, bv.w};

    float4* __restrict__ zv = reinterpret_cast<float4*>(z)
        + ((size_t)b * TT + (size_t)p * CC) * NNV + n4;

    #pragma unroll
    for (int j = 0; j < CC; ++j) {
        float o[4];
        #pragma unroll
        for (int c = 0; c < 4; ++c) {
            const bool sp = (((bw[c] >> j) & 1u) != 0u) & (j >= ea[c]);
            if (sp) ea[c] = j + 6;
            o[c] = sp ? 1.0f : 0.0f;
        }
        zv[(size_t)j * NNV] = make_float4(o[0], o[1], o[2], o[3]);
    }
}

extern "C" void kernel_launch(void* const* d_in, const int* in_sizes, int n_in,
                              void* d_out, int out_size, void* d_ws, size_t ws_size,
                              hipStream_t stream) {
    const float* x = (const float*)d_in[0];
    float* z = (float*)d_out;

    // ws layout: tbl 4 MiB | bits 4 MiB | entry 1 MiB
    uint32_t* tbl = (uint32_t*)d_ws;
    uint32_t* bits_g = (uint32_t*)((char*)d_ws + (size_t)BB * PP * NN * 4);
    uint8_t*  entry  = (uint8_t*)((char*)d_ws + (size_t)BB * PP * NN * 8);

    refrac_scan<<<dim3(BB * PG), 256, 0, stream>>>(x, tbl, bits_g);
    refrac_compose<<<dim3(BB), 256, 0, stream>>>(tbl, entry);
    refrac_emit<<<dim3(BB * PG), 256, 0, stream>>>(bits_g, entry, z);
}